// Round 18
// baseline (148.726 us; speedup 1.0000x reference)
//
#include <hip/hip_runtime.h>

#define NB 4
#define NC 256
#define NHW 4096
#define NW 64
#define NTOPK 100
#define CANDE 32
#define FMARGIN 4.1f

typedef float f32x4 __attribute__((ext_vector_type(4)));

__device__ __forceinline__ unsigned int tokey(float f) {
    unsigned int u = __float_as_uint(f);
    return (u & 0x80000000u) ? ~u : (u | 0x80000000u);
}
__device__ __forceinline__ float k16tof(unsigned int k) {
    unsigned int k32 = k << 16;
    return __uint_as_float((k32 & 0x80000000u) ? (k32 ^ 0x80000000u) : ~k32);
}

// ==== fused pre-pass: [0,64) anchor | [64,320) packB | [320,576) packA ====
__global__ void k_pre(const float* __restrict__ sk, const float* __restrict__ rf,
                      const float* __restrict__ G,
                      int* __restrict__ ac_flat, int* __restrict__ pvalid,
                      unsigned char* __restrict__ refP, unsigned char* __restrict__ skT) {
    const int bid = blockIdx.x;
    if (bid < 64) {
        int t = bid * 256 + threadIdx.x;
        int b = t >> 12, p = t & (NHW - 1);
        float gxv = G[((size_t)b * NHW + p) * 2 + 0] * 64.0f;
        float gyv = G[((size_t)b * NHW + p) * 2 + 1] * 64.0f;
        float x0 = floorf(gxv), y0 = floorf(gyv);
        float cx[4] = {x0, x0 + 1.f, x0 + 1.f, x0};
        float cy[4] = {y0, y0, y0 + 1.f, y0 + 1.f};
        float d[4]; bool v[4]; float maxd = -INFINITY; bool any = false;
        #pragma unroll
        for (int i = 0; i < 4; ++i) {
            float dx = gxv - cx[i], dy = gyv - cy[i];
            d[i] = sqrtf(dx * dx + dy * dy);
            v[i] = (cx[i] >= 0.f) && (cy[i] >= 0.f) && (cx[i] <= 63.f) && (cy[i] <= 63.f);
            any = any || v[i];
            maxd = fmaxf(maxd, d[i]);
        }
        int sel = 0; float best = -INFINITY;
        #pragma unroll
        for (int i = 0; i < 4; ++i) {
            float prob = v[i] ? ((maxd + 0.3f) - d[i]) : -INFINITY;
            if (prob > best) { best = prob; sel = i; }
        }
        int acx = (int)cx[sel], acy = (int)cy[sel];
        int af = acy * NW + acx;
        af = af < 0 ? 0 : (af > NHW - 1 ? NHW - 1 : af);
        ac_flat[t] = af;
        pvalid[t] = any ? 1 : 0;
        return;
    }
    __shared__ float tile[64][NC + 1];
    __shared__ float psum[4][64];
    __shared__ float invs[64];
    const bool isB = bid < 320;
    const int blk = isB ? (bid - 64) : (bid - 320);
    const int b = blk >> 6;
    const int q0 = (blk & 63) << 6;
    const int t = threadIdx.x;
    const int qloc = t & 63;
    const int c0 = t >> 6;
    const float* base = (isB ? rf : sk) + (size_t)b * NC * NHW + q0 + qloc;
    #pragma unroll 8
    for (int cc = 0; cc < NC; cc += 4) {
        int c = cc + c0;
        tile[qloc][c] = base[(size_t)c * NHW];
    }
    __syncthreads();
    {
        float s = 0.f;
        #pragma unroll 8
        for (int j = 0; j < 64; ++j) { float v = tile[qloc][c0 * 64 + j]; s = fmaf(v, v, s); }
        psum[c0][qloc] = s;
    }
    __syncthreads();
    if (t < 64)
        invs[t] = 1.f / fmaxf(sqrtf(psum[0][t] + psum[1][t] + psum[2][t] + psum[3][t]), 1e-8f);
    __syncthreads();
    if (isB) {
        #pragma unroll
        for (int it = 0; it < 8; ++it) {
            int slot = it * 256 + t;
            int qt = slot >> 9;
            int kt = (slot >> 6) & 7;
            int lane = slot & 63;
            int g = lane >> 4, qll = lane & 15;
            int ql2 = (qt << 4) + qll;
            int c = kt * 32 + g * 8;
            const float iv = invs[ql2];
            unsigned int r0 = 0u, r1 = 0u;
            r0 = __builtin_amdgcn_cvt_pk_fp8_f32(tile[ql2][c + 0] * iv, tile[ql2][c + 1] * iv, r0, false);
            r0 = __builtin_amdgcn_cvt_pk_fp8_f32(tile[ql2][c + 2] * iv, tile[ql2][c + 3] * iv, r0, true);
            r1 = __builtin_amdgcn_cvt_pk_fp8_f32(tile[ql2][c + 4] * iv, tile[ql2][c + 5] * iv, r1, false);
            r1 = __builtin_amdgcn_cvt_pk_fp8_f32(tile[ql2][c + 6] * iv, tile[ql2][c + 7] * iv, r1, true);
            size_t oidx = (((size_t)(b * 256 + (q0 >> 4) + qt) * 8 + kt) * 64 + lane) * 8;
            *(uint2*)(refP + oidx) = make_uint2(r0, r1);
        }
    } else {
        const int row = t >> 2, seg = (t & 3) * 64;
        const float iv = invs[row];
        unsigned char* out = skT + ((size_t)b * NHW + q0 + row) * NC + seg;
        #pragma unroll
        for (int j0 = 0; j0 < 64; j0 += 8) {
            unsigned int r0 = 0u, r1 = 0u;
            r0 = __builtin_amdgcn_cvt_pk_fp8_f32(tile[row][seg + j0 + 0] * iv, tile[row][seg + j0 + 1] * iv, r0, false);
            r0 = __builtin_amdgcn_cvt_pk_fp8_f32(tile[row][seg + j0 + 2] * iv, tile[row][seg + j0 + 3] * iv, r0, true);
            r1 = __builtin_amdgcn_cvt_pk_fp8_f32(tile[row][seg + j0 + 4] * iv, tile[row][seg + j0 + 5] * iv, r1, false);
            r1 = __builtin_amdgcn_cvt_pk_fp8_f32(tile[row][seg + j0 + 6] * iv, tile[row][seg + j0 + 7] * iv, r1, true);
            *(uint2*)(out + j0) = make_uint2(r0, r1);
        }
    }
}

// ==== EIGHTH BLOCK: 8192 blocks x 512 thr; 16 rows x 512 cols; 20.8 KB LDS
// GEMM 4 tiles/wave; selection 2 rows/wave x 8 key-regs (half of R17's 16).
// Exact per-part top-32 (ties by (key,col)); 8 parts x 32 = 256 cands/row
// (stride + k_merge unchanged). Key LDS row-stride 520 staggers the 8-way
// row-pair write aliasing.
__global__ void k_part(const unsigned char* __restrict__ refP,
                       const unsigned char* __restrict__ skT,
                       const int* __restrict__ ac_flat,
                       float* __restrict__ cppg, unsigned int* __restrict__ cand) {
    __shared__ unsigned int key2e[8][520];                   // 16.6 KB row-pairs
    __shared__ __align__(16) unsigned char ancsA[8][64][8];  // 4 KB

    const int tid = threadIdx.x;
    const int lane = tid & 63;
    const int w = tid >> 6;          // wave 0..7
    const int g = lane >> 4;
    const int ql = lane & 15;
    const int lblk = (blockIdx.x & 7) * 1024 + (blockIdx.x >> 3);  // XCD swizzle
    const int e = lblk & 7;                  // eighth (512-col slab)
    const int rg = (lblk >> 3) & 255;
    const int b = lblk >> 11;
    const int p0 = rg << 4;

    // phase A: anchors (first 256 threads: 16 channels of one row each)
    if (tid < 256) {
        const int r = tid >> 4;
        const int ch = (tid & 15) << 4;
        const int a = ac_flat[b * NHW + p0 + r];
        uint4 v = *(const uint4*)(skT + ((size_t)b * NHW + a) * NC + ch);
        const int kk = ch >> 5;
        const int g1 = (ch >> 3) & 3;
        *(uint2*)&ancsA[kk][g1 * 16 + r][0] = make_uint2(v.x, v.y);
        *(uint2*)&ancsA[kk][(g1 + 1) * 16 + r][0] = make_uint2(v.z, v.w);
    }
    __syncthreads();

    long long af0 = *(const long long*)&ancsA[0][lane][0];
    long long af1 = *(const long long*)&ancsA[1][lane][0];
    long long af2 = *(const long long*)&ancsA[2][lane][0];
    long long af3 = *(const long long*)&ancsA[3][lane][0];
    long long af4 = *(const long long*)&ancsA[4][lane][0];
    long long af5 = *(const long long*)&ancsA[5][lane][0];
    long long af6 = *(const long long*)&ancsA[6][lane][0];
    long long af7 = *(const long long*)&ancsA[7][lane][0];

    const bool eDiag = (p0 >> 9) == e;
    const int tq = (p0 & 511) >> 4;           // diag col-tile within eighth 0..31
    const int wstar = tq >> 2, tstar = tq & 3;

    // phase B: 4 tiles/wave (col-tiles ct = w*4+t of this 512-col slab)
    #pragma unroll
    for (int t = 0; t < 4; ++t) {
        f32x4 a4 = (f32x4){0.f, 0.f, 0.f, 0.f};
        const unsigned char* bpt =
            refP + (((size_t)(b * 256 + e * 32 + w * 4 + t) * 8) * 64 + lane) * 8;
        a4 = __builtin_amdgcn_mfma_f32_16x16x32_fp8_fp8(af0, *(const long long*)(bpt + 0 * 512), a4, 0, 0, 0);
        a4 = __builtin_amdgcn_mfma_f32_16x16x32_fp8_fp8(af1, *(const long long*)(bpt + 1 * 512), a4, 0, 0, 0);
        a4 = __builtin_amdgcn_mfma_f32_16x16x32_fp8_fp8(af2, *(const long long*)(bpt + 2 * 512), a4, 0, 0, 0);
        a4 = __builtin_amdgcn_mfma_f32_16x16x32_fp8_fp8(af3, *(const long long*)(bpt + 3 * 512), a4, 0, 0, 0);
        a4 = __builtin_amdgcn_mfma_f32_16x16x32_fp8_fp8(af4, *(const long long*)(bpt + 4 * 512), a4, 0, 0, 0);
        a4 = __builtin_amdgcn_mfma_f32_16x16x32_fp8_fp8(af5, *(const long long*)(bpt + 5 * 512), a4, 0, 0, 0);
        a4 = __builtin_amdgcn_mfma_f32_16x16x32_fp8_fp8(af6, *(const long long*)(bpt + 6 * 512), a4, 0, 0, 0);
        a4 = __builtin_amdgcn_mfma_f32_16x16x32_fp8_fp8(af7, *(const long long*)(bpt + 7 * 512), a4, 0, 0, 0);
        if (eDiag && w == wstar && t == tstar) {
            #pragma unroll
            for (int i = 0; i < 4; ++i)
                if (ql == g * 4 + i) cppg[b * NHW + p0 + g * 4 + i] = a4[i];
        }
        unsigned int k01 = (tokey(a4[0]) >> 16) | ((tokey(a4[1]) >> 16) << 16);
        unsigned int k23 = (tokey(a4[2]) >> 16) | ((tokey(a4[3]) >> 16) << 16);
        const int ct = w * 4 + t;                 // col-tile 0..31 in slab
        const int pos = (ql << 5) + (ct ^ ql);    // bijective per ql
        key2e[2 * g + 0][pos] = k01;
        key2e[2 * g + 1][pos] = k23;
    }
    __syncthreads();

    // selection: wave w handles rows 2w, 2w+1; exact top-32 of this slab
    #pragma unroll 1
    for (int rr = 0; rr < 2; ++rr) {
        const int r = w * 2 + rr;
        const int rp = r >> 1;
        const int hsh = (r & 1) << 4;
        unsigned int ku[8];   // col c = lane*8 + j; (ct,ql)=(c>>4, c&15)
        #pragma unroll
        for (int j = 0; j < 8; ++j) {
            const int c = lane * 8 + j;
            ku[j] = (key2e[rp][((c & 15) << 5) + ((c >> 4) ^ (c & 15))] >> hsh) & 0xFFFFu;
        }

        unsigned int Ks = 0x4000u;
        int blw = 0;                      // count(< Ks), tracked in-search
        #pragma unroll 1
        for (int bit = 14; bit >= 0; --bit) {
            const unsigned int T = Ks | (1u << bit);
            int c = 0;
            #pragma unroll
            for (int j = 0; j < 8; ++j)
                c += __popcll(__ballot(ku[j] < T));
            if (c < CANDE) { Ks = T; blw = c; }
        }
        const int tk = CANDE - blw;

        int nlt = 0, ltc = 0;
        #pragma unroll
        for (int j = 0; j < 8; ++j) {
            nlt += (ku[j] < Ks) ? 1 : 0;
            ltc += (ku[j] == Ks) ? 1 : 0;
        }
        int packed = nlt | (ltc << 16);   // single packed exclusive scan
        int pscan = packed;
        #pragma unroll
        for (int d = 1; d < 64; d <<= 1) {
            int t2 = __shfl_up(pscan, d, 64);
            if (lane >= d) pscan += t2;
        }
        pscan -= packed;
        const int nltpfx = pscan & 0xFFFF;
        const int tpfx = pscan >> 16;

        unsigned int* crow = cand + ((size_t)(b * NHW + p0 + r)) * 256 + e * CANDE;
        int si = 0, mt = 0;
        #pragma unroll
        for (int j = 0; j < 8; ++j) {
            const unsigned int gc = (unsigned)(e * 512 + lane * 8 + j);
            if (ku[j] < Ks) {
                crow[nltpfx + si] = (ku[j] << 12) | gc;
                si++;
            } else if (ku[j] == Ks) {
                if (tpfx + mt < tk) crow[blw + tpfx + mt] = (Ks << 12) | gc;
                mt++;
            }
        }
    }
}

// ---- merge: 1 wave/row; exact top-100 of 256 candidates; filter; mean ----
__global__ void k_merge(const unsigned int* __restrict__ cand, const float* __restrict__ cppg,
                        const float* __restrict__ G, const int* __restrict__ pvalid,
                        float* __restrict__ row_val, int* __restrict__ row_valid) {
    const int lane = threadIdx.x & 63;
    const int w = threadIdx.x >> 6;
    const int row = blockIdx.x * 8 + w;       // = b*NHW + p
    const int b = row >> 12;
    const int pg = row & 4095;
    uint4 v = *(const uint4*)&cand[(size_t)row * 256 + lane * 4];
    unsigned int pk[4] = {v.x, v.y, v.z, v.w};

    unsigned int Ks = 0x4000u << 12;          // packed values unique -> tie-free
    #pragma unroll 1
    for (int bit = 25; bit >= 0; --bit) {
        const unsigned int T = Ks | (1u << bit);
        int c = 0;
        #pragma unroll
        for (int j = 0; j < 4; ++j)
            c += __popcll(__ballot(pk[j] < T));
        if (c < NTOPK) Ks = T;
    }

    const float dpos = 1.0f - cppg[row];
    const float2 gp = *(const float2*)&G[(size_t)row * 2];
    const float px = gp.x * 4096.f, py = gp.y * 4096.f;
    const float base_add = dpos + (FMARGIN - 1.0f);

    float fl = 0.f; int ccnt = 0;
    #pragma unroll
    for (int j = 0; j < 4; ++j) {
        if (pk[j] <= Ks) {
            const int q = (int)(pk[j] & 4095u);
            bool keep = (q != pg);
            if (keep) {
                float2 g2 = *(const float2*)&G[((size_t)(b * NHW + q)) * 2];
                float dx = fabsf(g2.x * 4096.f - px), dy = fabsf(g2.y * 4096.f - py);
                keep = !((dx < 1.2f) && (dy < 1.2f));
            }
            if (keep) { fl += base_add + k16tof(pk[j] >> 12); ccnt++; }
        }
    }
    #pragma unroll
    for (int d = 1; d < 64; d <<= 1) {
        fl += __shfl_xor(fl, d, 64);
        ccnt += __shfl_xor(ccnt, d, 64);
    }
    if (lane == 0) {
        const int pv = (pvalid[row] != 0) && (ccnt > 0);
        row_val[row] = pv ? (fl / (float)ccnt) : 0.f;
        row_valid[row] = pv;
    }
}

// ==== FALLBACK: R12 fused kernel (verbatim; proven) ====
__global__ __attribute__((amdgpu_flat_work_group_size(1024, 1024), amdgpu_waves_per_eu(4, 4)))
void k_main_r12(const unsigned char* __restrict__ refP, const unsigned char* __restrict__ skT,
                const float* __restrict__ G,
                const int* __restrict__ ac_flat, const int* __restrict__ pvalid,
                float* __restrict__ row_val, int* __restrict__ row_valid)
{
    __shared__ unsigned int key2[8][NHW];
    __shared__ __align__(16) unsigned char ancsA[8][64][8];
    __shared__ float cpp[16];

    const int tid = threadIdx.x;
    const int lane = tid & 63;
    const int w = tid >> 6;
    const int g = lane >> 4;
    const int ql = lane & 15;
    const int lblk = (blockIdx.x & 7) * 128 + (blockIdx.x >> 3);
    const int b = lblk >> 8;
    const int p0 = (lblk & 255) << 4;

    {
        const int a = ac_flat[b * NHW + p0 + w];
        const unsigned char* src = skT + ((size_t)b * NHW + a) * NC;
        unsigned int v = *(const unsigned int*)(src + lane * 4);
        const int c = lane * 4;
        const int kk = c >> 5, gg = (c >> 3) & 3, j = c & 7;
        *(unsigned int*)&ancsA[kk][gg * 16 + w][j] = v;
    }
    __syncthreads();

    const int wstar = p0 >> 8;
    const int tstar = (p0 >> 4) & 15;
    long long af0 = *(const long long*)&ancsA[0][lane][0];
    long long af1 = *(const long long*)&ancsA[1][lane][0];
    long long af2 = *(const long long*)&ancsA[2][lane][0];
    long long af3 = *(const long long*)&ancsA[3][lane][0];
    long long af4 = *(const long long*)&ancsA[4][lane][0];
    long long af5 = *(const long long*)&ancsA[5][lane][0];
    long long af6 = *(const long long*)&ancsA[6][lane][0];
    long long af7 = *(const long long*)&ancsA[7][lane][0];

    #pragma unroll 4
    for (int t = 0; t < 16; ++t) {
        f32x4 a4 = (f32x4){0.f, 0.f, 0.f, 0.f};
        const unsigned char* bpt =
            refP + (((size_t)(b * 256 + w * 16 + t) * 8) * 64 + lane) * 8;
        a4 = __builtin_amdgcn_mfma_f32_16x16x32_fp8_fp8(af0, *(const long long*)(bpt + 0 * 512), a4, 0, 0, 0);
        a4 = __builtin_amdgcn_mfma_f32_16x16x32_fp8_fp8(af1, *(const long long*)(bpt + 1 * 512), a4, 0, 0, 0);
        a4 = __builtin_amdgcn_mfma_f32_16x16x32_fp8_fp8(af2, *(const long long*)(bpt + 2 * 512), a4, 0, 0, 0);
        a4 = __builtin_amdgcn_mfma_f32_16x16x32_fp8_fp8(af3, *(const long long*)(bpt + 3 * 512), a4, 0, 0, 0);
        a4 = __builtin_amdgcn_mfma_f32_16x16x32_fp8_fp8(af4, *(const long long*)(bpt + 4 * 512), a4, 0, 0, 0);
        a4 = __builtin_amdgcn_mfma_f32_16x16x32_fp8_fp8(af5, *(const long long*)(bpt + 5 * 512), a4, 0, 0, 0);
        a4 = __builtin_amdgcn_mfma_f32_16x16x32_fp8_fp8(af6, *(const long long*)(bpt + 6 * 512), a4, 0, 0, 0);
        a4 = __builtin_amdgcn_mfma_f32_16x16x32_fp8_fp8(af7, *(const long long*)(bpt + 7 * 512), a4, 0, 0, 0);
        if (w == wstar && t == tstar) {
            #pragma unroll
            for (int i = 0; i < 4; ++i)
                if (ql == g * 4 + i) cpp[g * 4 + i] = a4[i];
        }
        unsigned int k01 = (tokey(a4[0]) >> 16) | ((tokey(a4[1]) >> 16) << 16);
        unsigned int k23 = (tokey(a4[2]) >> 16) | ((tokey(a4[3]) >> 16) << 16);
        const int l_r = (w << 2) + (t >> 2);
        const int ach = ((t & 3) << 2) + (ql >> 2);
        const int pidx = (l_r << 6) + ((ach ^ (l_r & 15)) << 2) + (ql & 3);
        key2[(g << 1) + 0][pidx] = k01;
        key2[(g << 1) + 1][pidx] = k23;
    }
    __syncthreads();

    const int rp = w >> 1;
    const int half = w & 1;
    unsigned int ku[64];
    #pragma unroll
    for (int ach = 0; ach < 16; ++ach) {
        const uint4 v = *(const uint4*)&key2[rp][(lane << 6) + ((ach ^ (lane & 15)) << 2)];
        ku[4 * ach + 0] = half ? (v.x >> 16) : (v.x & 0xFFFFu);
        ku[4 * ach + 1] = half ? (v.y >> 16) : (v.y & 0xFFFFu);
        ku[4 * ach + 2] = half ? (v.z >> 16) : (v.z & 0xFFFFu);
        ku[4 * ach + 3] = half ? (v.w >> 16) : (v.w & 0xFFFFu);
    }
    unsigned int Ks = 0x4000u;
    #pragma unroll 1
    for (int bit = 14; bit >= 0; --bit) {
        const unsigned int T = Ks | (1u << bit);
        int c = 0;
        #pragma unroll
        for (int j = 0; j < 64; ++j)
            c += __popcll(__ballot(ku[j] < T));
        if (c < NTOPK) Ks = T;
    }
    int below = 0;
    #pragma unroll
    for (int j = 0; j < 64; ++j)
        below += __popcll(__ballot(ku[j] < Ks));
    const int tk = NTOPK - below;

    const float dpos = 1.0f - cpp[w];
    const int pg = p0 + w;
    const float2 gp = *(const float2*)&G[((size_t)b * NHW + pg) * 2];
    const float px = gp.x * 4096.f, py = gp.y * 4096.f;
    const float base_add = dpos + (FMARGIN - 1.0f);

    float sumv = 0.f; int cnt = 0;
    unsigned long long tmask = 0ull; int ltc = 0;
    #pragma unroll
    for (int j = 0; j < 64; ++j) {
        const unsigned int k = ku[j];
        if (k < Ks) {
            const int q = (lane << 6) + 8 * (j >> 2) + 2 * (j & 3) + half;
            bool keep = (q != pg);
            if (keep) {
                float2 g2 = *(const float2*)&G[((size_t)b * NHW + q) * 2];
                float dx = fabsf(g2.x * 4096.f - px), dy = fabsf(g2.y * 4096.f - py);
                keep = !((dx < 1.2f) && (dy < 1.2f));
            }
            if (keep) { sumv += k16tof(k); cnt++; }
        } else if (k == Ks) {
            tmask |= (1ull << j);
            ltc++;
        }
    }
    int pfx = ltc;
    #pragma unroll
    for (int d = 1; d < 64; d <<= 1) {
        int t2 = __shfl_up(pfx, d, 64);
        if (lane >= d) pfx += t2;
    }
    pfx -= ltc;
    int ek = 0;
    if (ltc > 0 && pfx < tk) {
        unsigned long long mm = tmask;
        int m = 0;
        while (mm) {
            const int j = __ffsll((unsigned long long)mm) - 1;
            mm &= mm - 1;
            if (pfx + m < tk) {
                const int q = (lane << 6) + 8 * (j >> 2) + 2 * (j & 3) + half;
                bool keep = (q != pg);
                if (keep) {
                    float2 g2 = *(const float2*)&G[((size_t)b * NHW + q) * 2];
                    float dx = fabsf(g2.x * 4096.f - px), dy = fabsf(g2.y * 4096.f - py);
                    keep = !((dx < 1.2f) && (dy < 1.2f));
                }
                if (keep) ek++;
            }
            m++;
        }
    }
    const float vstar = k16tof(Ks);
    float fl = sumv + (float)cnt * base_add + (float)ek * (base_add + vstar);
    int ccnt = cnt + ek;
    #pragma unroll
    for (int d = 1; d < 64; d <<= 1) {
        fl += __shfl_xor(fl, d, 64);
        ccnt += __shfl_xor(ccnt, d, 64);
    }
    if (lane == 0) {
        const int pv = (pvalid[b * NHW + pg] != 0) && (ccnt > 0);
        row_val[b * NHW + pg] = pv ? (fl / (float)ccnt) : 0.f;
        row_valid[b * NHW + pg] = pv;
    }
}

// ---- final deterministic reduction (1024 threads) ----
__global__ void k_reduce(const float* __restrict__ row_val, const int* __restrict__ row_valid,
                         float* __restrict__ out) {
    __shared__ float ss[1024];
    __shared__ int sc[1024];
    float s = 0.f; int n = 0;
    for (int i = threadIdx.x; i < NB * NHW; i += 1024) { s += row_val[i]; n += row_valid[i]; }
    ss[threadIdx.x] = s; sc[threadIdx.x] = n;
    __syncthreads();
    for (int d = 512; d > 0; d >>= 1) {
        if (threadIdx.x < d) { ss[threadIdx.x] += ss[threadIdx.x + d]; sc[threadIdx.x] += sc[threadIdx.x + d]; }
        __syncthreads();
    }
    if (threadIdx.x == 0) out[0] = ss[0] / (1e-6f + (float)sc[0]);
}

extern "C" void kernel_launch(void* const* d_in, const int* in_sizes, int n_in,
                              void* d_out, int out_size, void* d_ws, size_t ws_size,
                              hipStream_t stream) {
    const float* sk = (const float*)d_in[0];
    const float* rf = (const float*)d_in[1];
    const float* G  = (const float*)d_in[2];
    char* ws = (char*)d_ws;
    const size_t SMALL5 = 5ull * 65536ull;
    const size_t PANEL8 = (size_t)NB * NC * NHW;              // 4 MB
    const size_t CANDSZ = (size_t)NB * NHW * 256 * 4;         // 16.8 MB
    const size_t QNEED = SMALL5 + 2 * PANEL8 + CANDSZ;        // ~25.5 MB
    int*   ac   = (int*)  (ws + 0 * 65536);
    int*   pv   = (int*)  (ws + 1 * 65536);
    float* rv_  = (float*)(ws + 2 * 65536);
    int*   rvd  = (int*)  (ws + 3 * 65536);
    float* cppg = (float*)(ws + 4 * 65536);
    unsigned char* rf8 = (unsigned char*)(ws + SMALL5);
    unsigned char* sk8 = (unsigned char*)(ws + SMALL5 + PANEL8);
    unsigned int* cand = (unsigned int*)(ws + SMALL5 + 2 * PANEL8);

    hipLaunchKernelGGL(k_pre, dim3(576), dim3(256), 0, stream,
                       sk, rf, G, ac, pv, rf8, sk8);
    if (ws_size >= QNEED) {
        hipLaunchKernelGGL(k_part, dim3(8192), dim3(512), 0, stream,
                           rf8, sk8, ac, cppg, cand);
        hipLaunchKernelGGL(k_merge, dim3(2048), dim3(512), 0, stream,
                           cand, cppg, G, pv, rv_, rvd);
    } else {
        hipLaunchKernelGGL(k_main_r12, dim3(1024), dim3(1024), 0, stream,
                           rf8, sk8, G, ac, pv, rv_, rvd);
    }
    hipLaunchKernelGGL(k_reduce, dim3(1), dim3(1024), 0, stream, rv_, rvd, (float*)d_out);
}

// Round 19
// 136.167 us; speedup vs baseline: 1.0922x; 1.0922x over previous
//
#include <hip/hip_runtime.h>

#define NB 4
#define NC 256
#define NHW 4096
#define NW 64
#define NTOPK 100
#define CANDE 32
#define FMARGIN 4.1f

typedef float f32x4 __attribute__((ext_vector_type(4)));

__device__ __forceinline__ unsigned int tokey(float f) {
    unsigned int u = __float_as_uint(f);
    return (u & 0x80000000u) ? ~u : (u | 0x80000000u);
}
__device__ __forceinline__ float k16tof(unsigned int k) {
    unsigned int k32 = k << 16;
    return __uint_as_float((k32 & 0x80000000u) ? (k32 ^ 0x80000000u) : ~k32);
}

// ==== fused pre-pass: [0,64) anchor | [64,320) packB | [320,576) packA ====
__global__ void k_pre(const float* __restrict__ sk, const float* __restrict__ rf,
                      const float* __restrict__ G,
                      int* __restrict__ ac_flat, int* __restrict__ pvalid,
                      unsigned char* __restrict__ refP, unsigned char* __restrict__ skT) {
    const int bid = blockIdx.x;
    if (bid < 64) {
        int t = bid * 256 + threadIdx.x;
        int b = t >> 12, p = t & (NHW - 1);
        float gxv = G[((size_t)b * NHW + p) * 2 + 0] * 64.0f;
        float gyv = G[((size_t)b * NHW + p) * 2 + 1] * 64.0f;
        float x0 = floorf(gxv), y0 = floorf(gyv);
        float cx[4] = {x0, x0 + 1.f, x0 + 1.f, x0};
        float cy[4] = {y0, y0, y0 + 1.f, y0 + 1.f};
        float d[4]; bool v[4]; float maxd = -INFINITY; bool any = false;
        #pragma unroll
        for (int i = 0; i < 4; ++i) {
            float dx = gxv - cx[i], dy = gyv - cy[i];
            d[i] = sqrtf(dx * dx + dy * dy);
            v[i] = (cx[i] >= 0.f) && (cy[i] >= 0.f) && (cx[i] <= 63.f) && (cy[i] <= 63.f);
            any = any || v[i];
            maxd = fmaxf(maxd, d[i]);
        }
        int sel = 0; float best = -INFINITY;
        #pragma unroll
        for (int i = 0; i < 4; ++i) {
            float prob = v[i] ? ((maxd + 0.3f) - d[i]) : -INFINITY;
            if (prob > best) { best = prob; sel = i; }
        }
        int acx = (int)cx[sel], acy = (int)cy[sel];
        int af = acy * NW + acx;
        af = af < 0 ? 0 : (af > NHW - 1 ? NHW - 1 : af);
        ac_flat[t] = af;
        pvalid[t] = any ? 1 : 0;
        return;
    }
    __shared__ float tile[64][NC + 1];
    __shared__ float psum[4][64];
    __shared__ float invs[64];
    const bool isB = bid < 320;
    const int blk = isB ? (bid - 64) : (bid - 320);
    const int b = blk >> 6;
    const int q0 = (blk & 63) << 6;
    const int t = threadIdx.x;
    const int qloc = t & 63;
    const int c0 = t >> 6;
    const float* base = (isB ? rf : sk) + (size_t)b * NC * NHW + q0 + qloc;
    #pragma unroll 8
    for (int cc = 0; cc < NC; cc += 4) {
        int c = cc + c0;
        tile[qloc][c] = base[(size_t)c * NHW];
    }
    __syncthreads();
    {
        float s = 0.f;
        #pragma unroll 8
        for (int j = 0; j < 64; ++j) { float v = tile[qloc][c0 * 64 + j]; s = fmaf(v, v, s); }
        psum[c0][qloc] = s;
    }
    __syncthreads();
    if (t < 64)
        invs[t] = 1.f / fmaxf(sqrtf(psum[0][t] + psum[1][t] + psum[2][t] + psum[3][t]), 1e-8f);
    __syncthreads();
    if (isB) {
        #pragma unroll
        for (int it = 0; it < 8; ++it) {
            int slot = it * 256 + t;
            int qt = slot >> 9;
            int kt = (slot >> 6) & 7;
            int lane = slot & 63;
            int g = lane >> 4, qll = lane & 15;
            int ql2 = (qt << 4) + qll;
            int c = kt * 32 + g * 8;
            const float iv = invs[ql2];
            unsigned int r0 = 0u, r1 = 0u;
            r0 = __builtin_amdgcn_cvt_pk_fp8_f32(tile[ql2][c + 0] * iv, tile[ql2][c + 1] * iv, r0, false);
            r0 = __builtin_amdgcn_cvt_pk_fp8_f32(tile[ql2][c + 2] * iv, tile[ql2][c + 3] * iv, r0, true);
            r1 = __builtin_amdgcn_cvt_pk_fp8_f32(tile[ql2][c + 4] * iv, tile[ql2][c + 5] * iv, r1, false);
            r1 = __builtin_amdgcn_cvt_pk_fp8_f32(tile[ql2][c + 6] * iv, tile[ql2][c + 7] * iv, r1, true);
            size_t oidx = (((size_t)(b * 256 + (q0 >> 4) + qt) * 8 + kt) * 64 + lane) * 8;
            *(uint2*)(refP + oidx) = make_uint2(r0, r1);
        }
    } else {
        const int row = t >> 2, seg = (t & 3) * 64;
        const float iv = invs[row];
        unsigned char* out = skT + ((size_t)b * NHW + q0 + row) * NC + seg;
        #pragma unroll
        for (int j0 = 0; j0 < 64; j0 += 8) {
            unsigned int r0 = 0u, r1 = 0u;
            r0 = __builtin_amdgcn_cvt_pk_fp8_f32(tile[row][seg + j0 + 0] * iv, tile[row][seg + j0 + 1] * iv, r0, false);
            r0 = __builtin_amdgcn_cvt_pk_fp8_f32(tile[row][seg + j0 + 2] * iv, tile[row][seg + j0 + 3] * iv, r0, true);
            r1 = __builtin_amdgcn_cvt_pk_fp8_f32(tile[row][seg + j0 + 4] * iv, tile[row][seg + j0 + 5] * iv, r1, false);
            r1 = __builtin_amdgcn_cvt_pk_fp8_f32(tile[row][seg + j0 + 6] * iv, tile[row][seg + j0 + 7] * iv, r1, true);
            *(uint2*)(out + j0) = make_uint2(r0, r1);
        }
    }
}

// per-row class-search selection over 8 key regs (bits 14..4, 11 iters);
// keeps exact strict-below + col-ordered boundary-class ties (<= 16-ulp class)
#define SELECT_ROW(KU, ROWIDX)                                                   \
    do {                                                                          \
        const int r = w * 2 + (ROWIDX);                                           \
        unsigned int Ks = 0x4000u;                                                \
        int blw = 0;                                                              \
        _Pragma("unroll 1")                                                       \
        for (int bit = 14; bit >= 4; --bit) {                                     \
            const unsigned int T = Ks | (1u << bit);                              \
            int c = 0;                                                            \
            _Pragma("unroll")                                                     \
            for (int j = 0; j < 8; ++j)                                           \
                c += __popcll(__ballot(KU[j] < T));                               \
            if (c < CANDE) { Ks = T; blw = c; }                                   \
        }                                                                         \
        const unsigned int Kt = Ks + 16u;                                         \
        const int tk = CANDE - blw;                                               \
        int nlt = 0, ltc = 0;                                                     \
        _Pragma("unroll")                                                         \
        for (int j = 0; j < 8; ++j) {                                             \
            nlt += (KU[j] < Ks) ? 1 : 0;                                          \
            ltc += (KU[j] >= Ks && KU[j] < Kt) ? 1 : 0;                           \
        }                                                                         \
        int packed = nlt | (ltc << 16);                                           \
        int pscan = packed;                                                       \
        _Pragma("unroll")                                                         \
        for (int d = 1; d < 64; d <<= 1) {                                        \
            int t2 = __shfl_up(pscan, d, 64);                                     \
            if (lane >= d) pscan += t2;                                           \
        }                                                                         \
        pscan -= packed;                                                          \
        const int nltpfx = pscan & 0xFFFF;                                        \
        const int tpfx = pscan >> 16;                                             \
        unsigned int* crow = cand + ((size_t)(b * NHW + p0 + r)) * 256 + e * CANDE; \
        int si = 0, mt = 0;                                                       \
        _Pragma("unroll")                                                         \
        for (int j = 0; j < 8; ++j) {                                             \
            const unsigned int gc = (unsigned)(e * 512 + lane * 8 + j);           \
            if (KU[j] < Ks) {                                                     \
                crow[nltpfx + si] = (KU[j] << 12) | gc;                           \
                si++;                                                             \
            } else if (KU[j] < Kt) {                                              \
                if (tpfx + mt < tk) crow[blw + tpfx + mt] = (KU[j] << 12) | gc;   \
                mt++;                                                             \
            }                                                                     \
        }                                                                         \
    } while (0)

// ==== EIGHTH BLOCK: 8192 blocks x 512 thr; 16 rows x 512 cols; 20.8 KB LDS
__global__ void k_part(const unsigned char* __restrict__ refP,
                       const unsigned char* __restrict__ skT,
                       const int* __restrict__ ac_flat,
                       float* __restrict__ cppg, unsigned int* __restrict__ cand) {
    __shared__ unsigned int key2e[8][520];                   // 16.6 KB row-pairs
    __shared__ __align__(16) unsigned char ancsA[8][64][8];  // 4 KB

    const int tid = threadIdx.x;
    const int lane = tid & 63;
    const int w = tid >> 6;          // wave 0..7
    const int g = lane >> 4;
    const int ql = lane & 15;
    const int lblk = (blockIdx.x & 7) * 1024 + (blockIdx.x >> 3);  // XCD swizzle
    const int e = lblk & 7;                  // eighth (512-col slab)
    const int rg = (lblk >> 3) & 255;
    const int b = lblk >> 11;
    const int p0 = rg << 4;

    // phase A: anchors (first 256 threads: 16 channels of one row each)
    if (tid < 256) {
        const int r = tid >> 4;
        const int ch = (tid & 15) << 4;
        const int a = ac_flat[b * NHW + p0 + r];
        uint4 v = *(const uint4*)(skT + ((size_t)b * NHW + a) * NC + ch);
        const int kk = ch >> 5;
        const int g1 = (ch >> 3) & 3;
        *(uint2*)&ancsA[kk][g1 * 16 + r][0] = make_uint2(v.x, v.y);
        *(uint2*)&ancsA[kk][(g1 + 1) * 16 + r][0] = make_uint2(v.z, v.w);
    }
    __syncthreads();

    long long af0 = *(const long long*)&ancsA[0][lane][0];
    long long af1 = *(const long long*)&ancsA[1][lane][0];
    long long af2 = *(const long long*)&ancsA[2][lane][0];
    long long af3 = *(const long long*)&ancsA[3][lane][0];
    long long af4 = *(const long long*)&ancsA[4][lane][0];
    long long af5 = *(const long long*)&ancsA[5][lane][0];
    long long af6 = *(const long long*)&ancsA[6][lane][0];
    long long af7 = *(const long long*)&ancsA[7][lane][0];

    const bool eDiag = (p0 >> 9) == e;
    const int tq = (p0 & 511) >> 4;           // diag col-tile within eighth 0..31
    const int wstar = tq >> 2, tstar = tq & 3;

    // phase B: 4 tiles/wave (col-tiles ct = w*4+t of this 512-col slab)
    #pragma unroll
    for (int t = 0; t < 4; ++t) {
        f32x4 a4 = (f32x4){0.f, 0.f, 0.f, 0.f};
        const unsigned char* bpt =
            refP + (((size_t)(b * 256 + e * 32 + w * 4 + t) * 8) * 64 + lane) * 8;
        a4 = __builtin_amdgcn_mfma_f32_16x16x32_fp8_fp8(af0, *(const long long*)(bpt + 0 * 512), a4, 0, 0, 0);
        a4 = __builtin_amdgcn_mfma_f32_16x16x32_fp8_fp8(af1, *(const long long*)(bpt + 1 * 512), a4, 0, 0, 0);
        a4 = __builtin_amdgcn_mfma_f32_16x16x32_fp8_fp8(af2, *(const long long*)(bpt + 2 * 512), a4, 0, 0, 0);
        a4 = __builtin_amdgcn_mfma_f32_16x16x32_fp8_fp8(af3, *(const long long*)(bpt + 3 * 512), a4, 0, 0, 0);
        a4 = __builtin_amdgcn_mfma_f32_16x16x32_fp8_fp8(af4, *(const long long*)(bpt + 4 * 512), a4, 0, 0, 0);
        a4 = __builtin_amdgcn_mfma_f32_16x16x32_fp8_fp8(af5, *(const long long*)(bpt + 5 * 512), a4, 0, 0, 0);
        a4 = __builtin_amdgcn_mfma_f32_16x16x32_fp8_fp8(af6, *(const long long*)(bpt + 6 * 512), a4, 0, 0, 0);
        a4 = __builtin_amdgcn_mfma_f32_16x16x32_fp8_fp8(af7, *(const long long*)(bpt + 7 * 512), a4, 0, 0, 0);
        if (eDiag && w == wstar && t == tstar) {
            #pragma unroll
            for (int i = 0; i < 4; ++i)
                if (ql == g * 4 + i) cppg[b * NHW + p0 + g * 4 + i] = a4[i];
        }
        unsigned int k01 = (tokey(a4[0]) >> 16) | ((tokey(a4[1]) >> 16) << 16);
        unsigned int k23 = (tokey(a4[2]) >> 16) | ((tokey(a4[3]) >> 16) << 16);
        const int ct = w * 4 + t;                 // col-tile 0..31 in slab
        const int pos = (ql << 5) + (ct ^ ql);    // bijective per ql
        key2e[2 * g + 0][pos] = k01;
        key2e[2 * g + 1][pos] = k23;
    }
    __syncthreads();

    // selection: wave w owns row-pair w (rows 2w, 2w+1); load dwords ONCE
    unsigned int kl[8], kh[8];
    #pragma unroll
    for (int j = 0; j < 8; ++j) {
        const int c = lane * 8 + j;
        const unsigned int kd = key2e[w][((c & 15) << 5) + ((c >> 4) ^ (c & 15))];
        kl[j] = kd & 0xFFFFu;
        kh[j] = kd >> 16;
    }
    SELECT_ROW(kl, 0);
    SELECT_ROW(kh, 1);
}

// ---- merge: 1 wave/row; exact top-100 of 256 candidates; filter; mean ----
__global__ void k_merge(const unsigned int* __restrict__ cand, const float* __restrict__ cppg,
                        const float* __restrict__ G, const int* __restrict__ pvalid,
                        float* __restrict__ row_val, int* __restrict__ row_valid) {
    const int lane = threadIdx.x & 63;
    const int w = threadIdx.x >> 6;
    const int row = blockIdx.x * 8 + w;       // = b*NHW + p
    const int b = row >> 12;
    const int pg = row & 4095;
    uint4 v = *(const uint4*)&cand[(size_t)row * 256 + lane * 4];
    unsigned int pk[4] = {v.x, v.y, v.z, v.w};

    unsigned int Ks = 0x4000u << 12;          // packed values unique -> tie-free
    #pragma unroll 1
    for (int bit = 25; bit >= 0; --bit) {
        const unsigned int T = Ks | (1u << bit);
        int c = 0;
        #pragma unroll
        for (int j = 0; j < 4; ++j)
            c += __popcll(__ballot(pk[j] < T));
        if (c < NTOPK) Ks = T;
    }

    const float dpos = 1.0f - cppg[row];
    const float2 gp = *(const float2*)&G[(size_t)row * 2];
    const float px = gp.x * 4096.f, py = gp.y * 4096.f;
    const float base_add = dpos + (FMARGIN - 1.0f);

    float fl = 0.f; int ccnt = 0;
    #pragma unroll
    for (int j = 0; j < 4; ++j) {
        if (pk[j] <= Ks) {
            const int q = (int)(pk[j] & 4095u);
            bool keep = (q != pg);
            if (keep) {
                float2 g2 = *(const float2*)&G[((size_t)(b * NHW + q)) * 2];
                float dx = fabsf(g2.x * 4096.f - px), dy = fabsf(g2.y * 4096.f - py);
                keep = !((dx < 1.2f) && (dy < 1.2f));
            }
            if (keep) { fl += base_add + k16tof(pk[j] >> 12); ccnt++; }
        }
    }
    #pragma unroll
    for (int d = 1; d < 64; d <<= 1) {
        fl += __shfl_xor(fl, d, 64);
        ccnt += __shfl_xor(ccnt, d, 64);
    }
    if (lane == 0) {
        const int pv = (pvalid[row] != 0) && (ccnt > 0);
        row_val[row] = pv ? (fl / (float)ccnt) : 0.f;
        row_valid[row] = pv;
    }
}

// ==== FALLBACK: R12 fused kernel (verbatim; proven) ====
__global__ __attribute__((amdgpu_flat_work_group_size(1024, 1024), amdgpu_waves_per_eu(4, 4)))
void k_main_r12(const unsigned char* __restrict__ refP, const unsigned char* __restrict__ skT,
                const float* __restrict__ G,
                const int* __restrict__ ac_flat, const int* __restrict__ pvalid,
                float* __restrict__ row_val, int* __restrict__ row_valid)
{
    __shared__ unsigned int key2[8][NHW];
    __shared__ __align__(16) unsigned char ancsA[8][64][8];
    __shared__ float cpp[16];

    const int tid = threadIdx.x;
    const int lane = tid & 63;
    const int w = tid >> 6;
    const int g = lane >> 4;
    const int ql = lane & 15;
    const int lblk = (blockIdx.x & 7) * 128 + (blockIdx.x >> 3);
    const int b = lblk >> 8;
    const int p0 = (lblk & 255) << 4;

    {
        const int a = ac_flat[b * NHW + p0 + w];
        const unsigned char* src = skT + ((size_t)b * NHW + a) * NC;
        unsigned int v = *(const unsigned int*)(src + lane * 4);
        const int c = lane * 4;
        const int kk = c >> 5, gg = (c >> 3) & 3, j = c & 7;
        *(unsigned int*)&ancsA[kk][gg * 16 + w][j] = v;
    }
    __syncthreads();

    const int wstar = p0 >> 8;
    const int tstar = (p0 >> 4) & 15;
    long long af0 = *(const long long*)&ancsA[0][lane][0];
    long long af1 = *(const long long*)&ancsA[1][lane][0];
    long long af2 = *(const long long*)&ancsA[2][lane][0];
    long long af3 = *(const long long*)&ancsA[3][lane][0];
    long long af4 = *(const long long*)&ancsA[4][lane][0];
    long long af5 = *(const long long*)&ancsA[5][lane][0];
    long long af6 = *(const long long*)&ancsA[6][lane][0];
    long long af7 = *(const long long*)&ancsA[7][lane][0];

    #pragma unroll 4
    for (int t = 0; t < 16; ++t) {
        f32x4 a4 = (f32x4){0.f, 0.f, 0.f, 0.f};
        const unsigned char* bpt =
            refP + (((size_t)(b * 256 + w * 16 + t) * 8) * 64 + lane) * 8;
        a4 = __builtin_amdgcn_mfma_f32_16x16x32_fp8_fp8(af0, *(const long long*)(bpt + 0 * 512), a4, 0, 0, 0);
        a4 = __builtin_amdgcn_mfma_f32_16x16x32_fp8_fp8(af1, *(const long long*)(bpt + 1 * 512), a4, 0, 0, 0);
        a4 = __builtin_amdgcn_mfma_f32_16x16x32_fp8_fp8(af2, *(const long long*)(bpt + 2 * 512), a4, 0, 0, 0);
        a4 = __builtin_amdgcn_mfma_f32_16x16x32_fp8_fp8(af3, *(const long long*)(bpt + 3 * 512), a4, 0, 0, 0);
        a4 = __builtin_amdgcn_mfma_f32_16x16x32_fp8_fp8(af4, *(const long long*)(bpt + 4 * 512), a4, 0, 0, 0);
        a4 = __builtin_amdgcn_mfma_f32_16x16x32_fp8_fp8(af5, *(const long long*)(bpt + 5 * 512), a4, 0, 0, 0);
        a4 = __builtin_amdgcn_mfma_f32_16x16x32_fp8_fp8(af6, *(const long long*)(bpt + 6 * 512), a4, 0, 0, 0);
        a4 = __builtin_amdgcn_mfma_f32_16x16x32_fp8_fp8(af7, *(const long long*)(bpt + 7 * 512), a4, 0, 0, 0);
        if (w == wstar && t == tstar) {
            #pragma unroll
            for (int i = 0; i < 4; ++i)
                if (ql == g * 4 + i) cpp[g * 4 + i] = a4[i];
        }
        unsigned int k01 = (tokey(a4[0]) >> 16) | ((tokey(a4[1]) >> 16) << 16);
        unsigned int k23 = (tokey(a4[2]) >> 16) | ((tokey(a4[3]) >> 16) << 16);
        const int l_r = (w << 2) + (t >> 2);
        const int ach = ((t & 3) << 2) + (ql >> 2);
        const int pidx = (l_r << 6) + ((ach ^ (l_r & 15)) << 2) + (ql & 3);
        key2[(g << 1) + 0][pidx] = k01;
        key2[(g << 1) + 1][pidx] = k23;
    }
    __syncthreads();

    const int rp = w >> 1;
    const int half = w & 1;
    unsigned int ku[64];
    #pragma unroll
    for (int ach = 0; ach < 16; ++ach) {
        const uint4 v = *(const uint4*)&key2[rp][(lane << 6) + ((ach ^ (lane & 15)) << 2)];
        ku[4 * ach + 0] = half ? (v.x >> 16) : (v.x & 0xFFFFu);
        ku[4 * ach + 1] = half ? (v.y >> 16) : (v.y & 0xFFFFu);
        ku[4 * ach + 2] = half ? (v.z >> 16) : (v.z & 0xFFFFu);
        ku[4 * ach + 3] = half ? (v.w >> 16) : (v.w & 0xFFFFu);
    }
    unsigned int Ks = 0x4000u;
    #pragma unroll 1
    for (int bit = 14; bit >= 0; --bit) {
        const unsigned int T = Ks | (1u << bit);
        int c = 0;
        #pragma unroll
        for (int j = 0; j < 64; ++j)
            c += __popcll(__ballot(ku[j] < T));
        if (c < NTOPK) Ks = T;
    }
    int below = 0;
    #pragma unroll
    for (int j = 0; j < 64; ++j)
        below += __popcll(__ballot(ku[j] < Ks));
    const int tk = NTOPK - below;

    const float dpos = 1.0f - cpp[w];
    const int pg = p0 + w;
    const float2 gp = *(const float2*)&G[((size_t)b * NHW + pg) * 2];
    const float px = gp.x * 4096.f, py = gp.y * 4096.f;
    const float base_add = dpos + (FMARGIN - 1.0f);

    float sumv = 0.f; int cnt = 0;
    unsigned long long tmask = 0ull; int ltc = 0;
    #pragma unroll
    for (int j = 0; j < 64; ++j) {
        const unsigned int k = ku[j];
        if (k < Ks) {
            const int q = (lane << 6) + 8 * (j >> 2) + 2 * (j & 3) + half;
            bool keep = (q != pg);
            if (keep) {
                float2 g2 = *(const float2*)&G[((size_t)b * NHW + q) * 2];
                float dx = fabsf(g2.x * 4096.f - px), dy = fabsf(g2.y * 4096.f - py);
                keep = !((dx < 1.2f) && (dy < 1.2f));
            }
            if (keep) { sumv += k16tof(k); cnt++; }
        } else if (k == Ks) {
            tmask |= (1ull << j);
            ltc++;
        }
    }
    int pfx = ltc;
    #pragma unroll
    for (int d = 1; d < 64; d <<= 1) {
        int t2 = __shfl_up(pfx, d, 64);
        if (lane >= d) pfx += t2;
    }
    pfx -= ltc;
    int ek = 0;
    if (ltc > 0 && pfx < tk) {
        unsigned long long mm = tmask;
        int m = 0;
        while (mm) {
            const int j = __ffsll((unsigned long long)mm) - 1;
            mm &= mm - 1;
            if (pfx + m < tk) {
                const int q = (lane << 6) + 8 * (j >> 2) + 2 * (j & 3) + half;
                bool keep = (q != pg);
                if (keep) {
                    float2 g2 = *(const float2*)&G[((size_t)b * NHW + q) * 2];
                    float dx = fabsf(g2.x * 4096.f - px), dy = fabsf(g2.y * 4096.f - py);
                    keep = !((dx < 1.2f) && (dy < 1.2f));
                }
                if (keep) ek++;
            }
            m++;
        }
    }
    const float vstar = k16tof(Ks);
    float fl = sumv + (float)cnt * base_add + (float)ek * (base_add + vstar);
    int ccnt = cnt + ek;
    #pragma unroll
    for (int d = 1; d < 64; d <<= 1) {
        fl += __shfl_xor(fl, d, 64);
        ccnt += __shfl_xor(ccnt, d, 64);
    }
    if (lane == 0) {
        const int pv = (pvalid[b * NHW + pg] != 0) && (ccnt > 0);
        row_val[b * NHW + pg] = pv ? (fl / (float)ccnt) : 0.f;
        row_valid[b * NHW + pg] = pv;
    }
}

// ---- final deterministic reduction (1024 threads) ----
__global__ void k_reduce(const float* __restrict__ row_val, const int* __restrict__ row_valid,
                         float* __restrict__ out) {
    __shared__ float ss[1024];
    __shared__ int sc[1024];
    float s = 0.f; int n = 0;
    for (int i = threadIdx.x; i < NB * NHW; i += 1024) { s += row_val[i]; n += row_valid[i]; }
    ss[threadIdx.x] = s; sc[threadIdx.x] = n;
    __syncthreads();
    for (int d = 512; d > 0; d >>= 1) {
        if (threadIdx.x < d) { ss[threadIdx.x] += ss[threadIdx.x + d]; sc[threadIdx.x] += sc[threadIdx.x + d]; }
        __syncthreads();
    }
    if (threadIdx.x == 0) out[0] = ss[0] / (1e-6f + (float)sc[0]);
}

extern "C" void kernel_launch(void* const* d_in, const int* in_sizes, int n_in,
                              void* d_out, int out_size, void* d_ws, size_t ws_size,
                              hipStream_t stream) {
    const float* sk = (const float*)d_in[0];
    const float* rf = (const float*)d_in[1];
    const float* G  = (const float*)d_in[2];
    char* ws = (char*)d_ws;
    const size_t SMALL5 = 5ull * 65536ull;
    const size_t PANEL8 = (size_t)NB * NC * NHW;              // 4 MB
    const size_t CANDSZ = (size_t)NB * NHW * 256 * 4;         // 16.8 MB
    const size_t QNEED = SMALL5 + 2 * PANEL8 + CANDSZ;        // ~25.5 MB
    int*   ac   = (int*)  (ws + 0 * 65536);
    int*   pv   = (int*)  (ws + 1 * 65536);
    float* rv_  = (float*)(ws + 2 * 65536);
    int*   rvd  = (int*)  (ws + 3 * 65536);
    float* cppg = (float*)(ws + 4 * 65536);
    unsigned char* rf8 = (unsigned char*)(ws + SMALL5);
    unsigned char* sk8 = (unsigned char*)(ws + SMALL5 + PANEL8);
    unsigned int* cand = (unsigned int*)(ws + SMALL5 + 2 * PANEL8);

    hipLaunchKernelGGL(k_pre, dim3(576), dim3(256), 0, stream,
                       sk, rf, G, ac, pv, rf8, sk8);
    if (ws_size >= QNEED) {
        hipLaunchKernelGGL(k_part, dim3(8192), dim3(512), 0, stream,
                           rf8, sk8, ac, cppg, cand);
        hipLaunchKernelGGL(k_merge, dim3(2048), dim3(512), 0, stream,
                           cand, cppg, G, pv, rv_, rvd);
    } else {
        hipLaunchKernelGGL(k_main_r12, dim3(1024), dim3(1024), 0, stream,
                           rf8, sk8, G, ac, pv, rv_, rvd);
    }
    hipLaunchKernelGGL(k_reduce, dim3(1), dim3(1024), 0, stream, rv_, rvd, (float*)d_out);
}

// Round 20
// 132.906 us; speedup vs baseline: 1.1190x; 1.0245x over previous
//
#include <hip/hip_runtime.h>

#define NB 4
#define NC 256
#define NHW 4096
#define NW 64
#define NTOPK 100
#define CANDE 32
#define FMARGIN 4.1f

typedef float f32x4 __attribute__((ext_vector_type(4)));

__device__ __forceinline__ unsigned int tokey(float f) {
    unsigned int u = __float_as_uint(f);
    return (u & 0x80000000u) ? ~u : (u | 0x80000000u);
}
__device__ __forceinline__ float k16tof(unsigned int k) {
    unsigned int k32 = k << 16;
    return __uint_as_float((k32 & 0x80000000u) ? (k32 ^ 0x80000000u) : ~k32);
}

// ==== fused pre-pass: [0,64) anchor | [64,320) packB | [320,576) packA ====
__global__ void k_pre(const float* __restrict__ sk, const float* __restrict__ rf,
                      const float* __restrict__ G,
                      int* __restrict__ ac_flat, int* __restrict__ pvalid,
                      unsigned char* __restrict__ refP, unsigned char* __restrict__ skT) {
    const int bid = blockIdx.x;
    if (bid < 64) {
        int t = bid * 256 + threadIdx.x;
        int b = t >> 12, p = t & (NHW - 1);
        float gxv = G[((size_t)b * NHW + p) * 2 + 0] * 64.0f;
        float gyv = G[((size_t)b * NHW + p) * 2 + 1] * 64.0f;
        float x0 = floorf(gxv), y0 = floorf(gyv);
        float cx[4] = {x0, x0 + 1.f, x0 + 1.f, x0};
        float cy[4] = {y0, y0, y0 + 1.f, y0 + 1.f};
        float d[4]; bool v[4]; float maxd = -INFINITY; bool any = false;
        #pragma unroll
        for (int i = 0; i < 4; ++i) {
            float dx = gxv - cx[i], dy = gyv - cy[i];
            d[i] = sqrtf(dx * dx + dy * dy);
            v[i] = (cx[i] >= 0.f) && (cy[i] >= 0.f) && (cx[i] <= 63.f) && (cy[i] <= 63.f);
            any = any || v[i];
            maxd = fmaxf(maxd, d[i]);
        }
        int sel = 0; float best = -INFINITY;
        #pragma unroll
        for (int i = 0; i < 4; ++i) {
            float prob = v[i] ? ((maxd + 0.3f) - d[i]) : -INFINITY;
            if (prob > best) { best = prob; sel = i; }
        }
        int acx = (int)cx[sel], acy = (int)cy[sel];
        int af = acy * NW + acx;
        af = af < 0 ? 0 : (af > NHW - 1 ? NHW - 1 : af);
        ac_flat[t] = af;
        pvalid[t] = any ? 1 : 0;
        return;
    }
    __shared__ float tile[64][NC + 1];
    __shared__ float psum[4][64];
    __shared__ float invs[64];
    const bool isB = bid < 320;
    const int blk = isB ? (bid - 64) : (bid - 320);
    const int b = blk >> 6;
    const int q0 = (blk & 63) << 6;
    const int t = threadIdx.x;
    const int qloc = t & 63;
    const int c0 = t >> 6;
    const float* base = (isB ? rf : sk) + (size_t)b * NC * NHW + q0 + qloc;
    #pragma unroll 8
    for (int cc = 0; cc < NC; cc += 4) {
        int c = cc + c0;
        tile[qloc][c] = base[(size_t)c * NHW];
    }
    __syncthreads();
    {
        float s = 0.f;
        #pragma unroll 8
        for (int j = 0; j < 64; ++j) { float v = tile[qloc][c0 * 64 + j]; s = fmaf(v, v, s); }
        psum[c0][qloc] = s;
    }
    __syncthreads();
    if (t < 64)
        invs[t] = 1.f / fmaxf(sqrtf(psum[0][t] + psum[1][t] + psum[2][t] + psum[3][t]), 1e-8f);
    __syncthreads();
    if (isB) {
        #pragma unroll
        for (int it = 0; it < 8; ++it) {
            int slot = it * 256 + t;
            int qt = slot >> 9;
            int kt = (slot >> 6) & 7;
            int lane = slot & 63;
            int g = lane >> 4, qll = lane & 15;
            int ql2 = (qt << 4) + qll;
            int c = kt * 32 + g * 8;
            const float iv = invs[ql2];
            unsigned int r0 = 0u, r1 = 0u;
            r0 = __builtin_amdgcn_cvt_pk_fp8_f32(tile[ql2][c + 0] * iv, tile[ql2][c + 1] * iv, r0, false);
            r0 = __builtin_amdgcn_cvt_pk_fp8_f32(tile[ql2][c + 2] * iv, tile[ql2][c + 3] * iv, r0, true);
            r1 = __builtin_amdgcn_cvt_pk_fp8_f32(tile[ql2][c + 4] * iv, tile[ql2][c + 5] * iv, r1, false);
            r1 = __builtin_amdgcn_cvt_pk_fp8_f32(tile[ql2][c + 6] * iv, tile[ql2][c + 7] * iv, r1, true);
            size_t oidx = (((size_t)(b * 256 + (q0 >> 4) + qt) * 8 + kt) * 64 + lane) * 8;
            *(uint2*)(refP + oidx) = make_uint2(r0, r1);
        }
    } else {
        const int row = t >> 2, seg = (t & 3) * 64;
        const float iv = invs[row];
        unsigned char* out = skT + ((size_t)b * NHW + q0 + row) * NC + seg;
        #pragma unroll
        for (int j0 = 0; j0 < 64; j0 += 8) {
            unsigned int r0 = 0u, r1 = 0u;
            r0 = __builtin_amdgcn_cvt_pk_fp8_f32(tile[row][seg + j0 + 0] * iv, tile[row][seg + j0 + 1] * iv, r0, false);
            r0 = __builtin_amdgcn_cvt_pk_fp8_f32(tile[row][seg + j0 + 2] * iv, tile[row][seg + j0 + 3] * iv, r0, true);
            r1 = __builtin_amdgcn_cvt_pk_fp8_f32(tile[row][seg + j0 + 4] * iv, tile[row][seg + j0 + 5] * iv, r1, false);
            r1 = __builtin_amdgcn_cvt_pk_fp8_f32(tile[row][seg + j0 + 6] * iv, tile[row][seg + j0 + 7] * iv, r1, true);
            *(uint2*)(out + j0) = make_uint2(r0, r1);
        }
    }
}

// ==== EIGHTH BLOCK: 8192 blocks x 512 thr; 16 rows x 512 cols; 20.8 KB LDS
// Selection: FUSED dual-row class search (bits 13..4 — bit 14 is provably
// degenerate since keys>=0x407F), two independent count chains per iteration
// (ILP 2), fused tie counts + interleaved prefix scans. Same candidate sets
// and tie semantics as R19.
__global__ void k_part(const unsigned char* __restrict__ refP,
                       const unsigned char* __restrict__ skT,
                       const int* __restrict__ ac_flat,
                       float* __restrict__ cppg, unsigned int* __restrict__ cand) {
    __shared__ unsigned int key2e[8][520];                   // 16.6 KB row-pairs
    __shared__ __align__(16) unsigned char ancsA[8][64][8];  // 4 KB

    const int tid = threadIdx.x;
    const int lane = tid & 63;
    const int w = tid >> 6;          // wave 0..7
    const int g = lane >> 4;
    const int ql = lane & 15;
    const int lblk = (blockIdx.x & 7) * 1024 + (blockIdx.x >> 3);  // XCD swizzle
    const int e = lblk & 7;                  // eighth (512-col slab)
    const int rg = (lblk >> 3) & 255;
    const int b = lblk >> 11;
    const int p0 = rg << 4;

    // phase A: anchors (first 256 threads: 16 channels of one row each)
    if (tid < 256) {
        const int r = tid >> 4;
        const int ch = (tid & 15) << 4;
        const int a = ac_flat[b * NHW + p0 + r];
        uint4 v = *(const uint4*)(skT + ((size_t)b * NHW + a) * NC + ch);
        const int kk = ch >> 5;
        const int g1 = (ch >> 3) & 3;
        *(uint2*)&ancsA[kk][g1 * 16 + r][0] = make_uint2(v.x, v.y);
        *(uint2*)&ancsA[kk][(g1 + 1) * 16 + r][0] = make_uint2(v.z, v.w);
    }
    __syncthreads();

    long long af0 = *(const long long*)&ancsA[0][lane][0];
    long long af1 = *(const long long*)&ancsA[1][lane][0];
    long long af2 = *(const long long*)&ancsA[2][lane][0];
    long long af3 = *(const long long*)&ancsA[3][lane][0];
    long long af4 = *(const long long*)&ancsA[4][lane][0];
    long long af5 = *(const long long*)&ancsA[5][lane][0];
    long long af6 = *(const long long*)&ancsA[6][lane][0];
    long long af7 = *(const long long*)&ancsA[7][lane][0];

    const bool eDiag = (p0 >> 9) == e;
    const int tq = (p0 & 511) >> 4;           // diag col-tile within eighth 0..31
    const int wstar = tq >> 2, tstar = tq & 3;

    // phase B: 4 tiles/wave (col-tiles ct = w*4+t of this 512-col slab)
    #pragma unroll
    for (int t = 0; t < 4; ++t) {
        f32x4 a4 = (f32x4){0.f, 0.f, 0.f, 0.f};
        const unsigned char* bpt =
            refP + (((size_t)(b * 256 + e * 32 + w * 4 + t) * 8) * 64 + lane) * 8;
        a4 = __builtin_amdgcn_mfma_f32_16x16x32_fp8_fp8(af0, *(const long long*)(bpt + 0 * 512), a4, 0, 0, 0);
        a4 = __builtin_amdgcn_mfma_f32_16x16x32_fp8_fp8(af1, *(const long long*)(bpt + 1 * 512), a4, 0, 0, 0);
        a4 = __builtin_amdgcn_mfma_f32_16x16x32_fp8_fp8(af2, *(const long long*)(bpt + 2 * 512), a4, 0, 0, 0);
        a4 = __builtin_amdgcn_mfma_f32_16x16x32_fp8_fp8(af3, *(const long long*)(bpt + 3 * 512), a4, 0, 0, 0);
        a4 = __builtin_amdgcn_mfma_f32_16x16x32_fp8_fp8(af4, *(const long long*)(bpt + 4 * 512), a4, 0, 0, 0);
        a4 = __builtin_amdgcn_mfma_f32_16x16x32_fp8_fp8(af5, *(const long long*)(bpt + 5 * 512), a4, 0, 0, 0);
        a4 = __builtin_amdgcn_mfma_f32_16x16x32_fp8_fp8(af6, *(const long long*)(bpt + 6 * 512), a4, 0, 0, 0);
        a4 = __builtin_amdgcn_mfma_f32_16x16x32_fp8_fp8(af7, *(const long long*)(bpt + 7 * 512), a4, 0, 0, 0);
        if (eDiag && w == wstar && t == tstar) {
            #pragma unroll
            for (int i = 0; i < 4; ++i)
                if (ql == g * 4 + i) cppg[b * NHW + p0 + g * 4 + i] = a4[i];
        }
        unsigned int k01 = (tokey(a4[0]) >> 16) | ((tokey(a4[1]) >> 16) << 16);
        unsigned int k23 = (tokey(a4[2]) >> 16) | ((tokey(a4[3]) >> 16) << 16);
        const int ct = w * 4 + t;                 // col-tile 0..31 in slab
        const int pos = (ql << 5) + (ct ^ ql);    // bijective per ql
        key2e[2 * g + 0][pos] = k01;
        key2e[2 * g + 1][pos] = k23;
    }
    __syncthreads();

    // selection: wave w owns row-pair w (rows 2w, 2w+1); dwords loaded ONCE
    unsigned int kl[8], kh[8];
    #pragma unroll
    for (int j = 0; j < 8; ++j) {
        const int c = lane * 8 + j;
        const unsigned int kd = key2e[w][((c & 15) << 5) + ((c >> 4) ^ (c & 15))];
        kl[j] = kd & 0xFFFFu;
        kh[j] = kd >> 16;
    }

    // fused dual-row class search: 10 iterations, two independent chains
    unsigned int KsL = 0x4000u, KsH = 0x4000u;
    int blwL = 0, blwH = 0;
    #pragma unroll 1
    for (int bit = 13; bit >= 4; --bit) {
        const unsigned int TL = KsL | (1u << bit);
        const unsigned int TH = KsH | (1u << bit);
        int cL = 0, cH = 0;
        #pragma unroll
        for (int j = 0; j < 8; ++j) {
            cL += __popcll(__ballot(kl[j] < TL));
            cH += __popcll(__ballot(kh[j] < TH));
        }
        if (cL < CANDE) { KsL = TL; blwL = cL; }
        if (cH < CANDE) { KsH = TH; blwH = cH; }
    }
    const unsigned int KtL = KsL + 16u, KtH = KsH + 16u;
    const int tkL = CANDE - blwL, tkH = CANDE - blwH;

    // fused tie counting + interleaved packed prefix scans
    int nltL = 0, ltcL = 0, nltH = 0, ltcH = 0;
    #pragma unroll
    for (int j = 0; j < 8; ++j) {
        nltL += (kl[j] < KsL) ? 1 : 0;
        ltcL += (kl[j] >= KsL && kl[j] < KtL) ? 1 : 0;
        nltH += (kh[j] < KsH) ? 1 : 0;
        ltcH += (kh[j] >= KsH && kh[j] < KtH) ? 1 : 0;
    }
    int packedL = nltL | (ltcL << 16);
    int packedH = nltH | (ltcH << 16);
    int sL = packedL, sH = packedH;
    #pragma unroll
    for (int d = 1; d < 64; d <<= 1) {
        int tL = __shfl_up(sL, d, 64);
        int tH = __shfl_up(sH, d, 64);
        if (lane >= d) { sL += tL; sH += tH; }
    }
    sL -= packedL; sH -= packedH;

    // write row 2w (low halves)
    {
        unsigned int* crow = cand + ((size_t)(b * NHW + p0 + 2 * w)) * 256 + e * CANDE;
        const int nltpfx = sL & 0xFFFF, tpfx = sL >> 16;
        int si = 0, mt = 0;
        #pragma unroll
        for (int j = 0; j < 8; ++j) {
            const unsigned int gc = (unsigned)(e * 512 + lane * 8 + j);
            if (kl[j] < KsL) { crow[nltpfx + si] = (kl[j] << 12) | gc; si++; }
            else if (kl[j] < KtL) {
                if (tpfx + mt < tkL) crow[blwL + tpfx + mt] = (kl[j] << 12) | gc;
                mt++;
            }
        }
    }
    // write row 2w+1 (high halves)
    {
        unsigned int* crow = cand + ((size_t)(b * NHW + p0 + 2 * w + 1)) * 256 + e * CANDE;
        const int nltpfx = sH & 0xFFFF, tpfx = sH >> 16;
        int si = 0, mt = 0;
        #pragma unroll
        for (int j = 0; j < 8; ++j) {
            const unsigned int gc = (unsigned)(e * 512 + lane * 8 + j);
            if (kh[j] < KsH) { crow[nltpfx + si] = (kh[j] << 12) | gc; si++; }
            else if (kh[j] < KtH) {
                if (tpfx + mt < tkH) crow[blwH + tpfx + mt] = (kh[j] << 12) | gc;
                mt++;
            }
        }
    }
}

// ---- merge: 1 wave/row; exact top-100 of 256 candidates; filter; mean ----
__global__ void k_merge(const unsigned int* __restrict__ cand, const float* __restrict__ cppg,
                        const float* __restrict__ G, const int* __restrict__ pvalid,
                        float* __restrict__ row_val, int* __restrict__ row_valid) {
    const int lane = threadIdx.x & 63;
    const int w = threadIdx.x >> 6;
    const int row = blockIdx.x * 8 + w;       // = b*NHW + p
    const int b = row >> 12;
    const int pg = row & 4095;
    uint4 v = *(const uint4*)&cand[(size_t)row * 256 + lane * 4];
    unsigned int pk[4] = {v.x, v.y, v.z, v.w};

    unsigned int Ks = 0x4000u << 12;          // packed values unique -> tie-free
    #pragma unroll 1
    for (int bit = 25; bit >= 0; --bit) {
        const unsigned int T = Ks | (1u << bit);
        int c = 0;
        #pragma unroll
        for (int j = 0; j < 4; ++j)
            c += __popcll(__ballot(pk[j] < T));
        if (c < NTOPK) Ks = T;
    }

    const float dpos = 1.0f - cppg[row];
    const float2 gp = *(const float2*)&G[(size_t)row * 2];
    const float px = gp.x * 4096.f, py = gp.y * 4096.f;
    const float base_add = dpos + (FMARGIN - 1.0f);

    float fl = 0.f; int ccnt = 0;
    #pragma unroll
    for (int j = 0; j < 4; ++j) {
        if (pk[j] <= Ks) {
            const int q = (int)(pk[j] & 4095u);
            bool keep = (q != pg);
            if (keep) {
                float2 g2 = *(const float2*)&G[((size_t)(b * NHW + q)) * 2];
                float dx = fabsf(g2.x * 4096.f - px), dy = fabsf(g2.y * 4096.f - py);
                keep = !((dx < 1.2f) && (dy < 1.2f));
            }
            if (keep) { fl += base_add + k16tof(pk[j] >> 12); ccnt++; }
        }
    }
    #pragma unroll
    for (int d = 1; d < 64; d <<= 1) {
        fl += __shfl_xor(fl, d, 64);
        ccnt += __shfl_xor(ccnt, d, 64);
    }
    if (lane == 0) {
        const int pv = (pvalid[row] != 0) && (ccnt > 0);
        row_val[row] = pv ? (fl / (float)ccnt) : 0.f;
        row_valid[row] = pv;
    }
}

// ==== FALLBACK: R12 fused kernel (verbatim; proven) ====
__global__ __attribute__((amdgpu_flat_work_group_size(1024, 1024), amdgpu_waves_per_eu(4, 4)))
void k_main_r12(const unsigned char* __restrict__ refP, const unsigned char* __restrict__ skT,
                const float* __restrict__ G,
                const int* __restrict__ ac_flat, const int* __restrict__ pvalid,
                float* __restrict__ row_val, int* __restrict__ row_valid)
{
    __shared__ unsigned int key2[8][NHW];
    __shared__ __align__(16) unsigned char ancsA[8][64][8];
    __shared__ float cpp[16];

    const int tid = threadIdx.x;
    const int lane = tid & 63;
    const int w = tid >> 6;
    const int g = lane >> 4;
    const int ql = lane & 15;
    const int lblk = (blockIdx.x & 7) * 128 + (blockIdx.x >> 3);
    const int b = lblk >> 8;
    const int p0 = (lblk & 255) << 4;

    {
        const int a = ac_flat[b * NHW + p0 + w];
        const unsigned char* src = skT + ((size_t)b * NHW + a) * NC;
        unsigned int v = *(const unsigned int*)(src + lane * 4);
        const int c = lane * 4;
        const int kk = c >> 5, gg = (c >> 3) & 3, j = c & 7;
        *(unsigned int*)&ancsA[kk][gg * 16 + w][j] = v;
    }
    __syncthreads();

    const int wstar = p0 >> 8;
    const int tstar = (p0 >> 4) & 15;
    long long af0 = *(const long long*)&ancsA[0][lane][0];
    long long af1 = *(const long long*)&ancsA[1][lane][0];
    long long af2 = *(const long long*)&ancsA[2][lane][0];
    long long af3 = *(const long long*)&ancsA[3][lane][0];
    long long af4 = *(const long long*)&ancsA[4][lane][0];
    long long af5 = *(const long long*)&ancsA[5][lane][0];
    long long af6 = *(const long long*)&ancsA[6][lane][0];
    long long af7 = *(const long long*)&ancsA[7][lane][0];

    #pragma unroll 4
    for (int t = 0; t < 16; ++t) {
        f32x4 a4 = (f32x4){0.f, 0.f, 0.f, 0.f};
        const unsigned char* bpt =
            refP + (((size_t)(b * 256 + w * 16 + t) * 8) * 64 + lane) * 8;
        a4 = __builtin_amdgcn_mfma_f32_16x16x32_fp8_fp8(af0, *(const long long*)(bpt + 0 * 512), a4, 0, 0, 0);
        a4 = __builtin_amdgcn_mfma_f32_16x16x32_fp8_fp8(af1, *(const long long*)(bpt + 1 * 512), a4, 0, 0, 0);
        a4 = __builtin_amdgcn_mfma_f32_16x16x32_fp8_fp8(af2, *(const long long*)(bpt + 2 * 512), a4, 0, 0, 0);
        a4 = __builtin_amdgcn_mfma_f32_16x16x32_fp8_fp8(af3, *(const long long*)(bpt + 3 * 512), a4, 0, 0, 0);
        a4 = __builtin_amdgcn_mfma_f32_16x16x32_fp8_fp8(af4, *(const long long*)(bpt + 4 * 512), a4, 0, 0, 0);
        a4 = __builtin_amdgcn_mfma_f32_16x16x32_fp8_fp8(af5, *(const long long*)(bpt + 5 * 512), a4, 0, 0, 0);
        a4 = __builtin_amdgcn_mfma_f32_16x16x32_fp8_fp8(af6, *(const long long*)(bpt + 6 * 512), a4, 0, 0, 0);
        a4 = __builtin_amdgcn_mfma_f32_16x16x32_fp8_fp8(af7, *(const long long*)(bpt + 7 * 512), a4, 0, 0, 0);
        if (w == wstar && t == tstar) {
            #pragma unroll
            for (int i = 0; i < 4; ++i)
                if (ql == g * 4 + i) cpp[g * 4 + i] = a4[i];
        }
        unsigned int k01 = (tokey(a4[0]) >> 16) | ((tokey(a4[1]) >> 16) << 16);
        unsigned int k23 = (tokey(a4[2]) >> 16) | ((tokey(a4[3]) >> 16) << 16);
        const int l_r = (w << 2) + (t >> 2);
        const int ach = ((t & 3) << 2) + (ql >> 2);
        const int pidx = (l_r << 6) + ((ach ^ (l_r & 15)) << 2) + (ql & 3);
        key2[(g << 1) + 0][pidx] = k01;
        key2[(g << 1) + 1][pidx] = k23;
    }
    __syncthreads();

    const int rp = w >> 1;
    const int half = w & 1;
    unsigned int ku[64];
    #pragma unroll
    for (int ach = 0; ach < 16; ++ach) {
        const uint4 v = *(const uint4*)&key2[rp][(lane << 6) + ((ach ^ (lane & 15)) << 2)];
        ku[4 * ach + 0] = half ? (v.x >> 16) : (v.x & 0xFFFFu);
        ku[4 * ach + 1] = half ? (v.y >> 16) : (v.y & 0xFFFFu);
        ku[4 * ach + 2] = half ? (v.z >> 16) : (v.z & 0xFFFFu);
        ku[4 * ach + 3] = half ? (v.w >> 16) : (v.w & 0xFFFFu);
    }
    unsigned int Ks = 0x4000u;
    #pragma unroll 1
    for (int bit = 14; bit >= 0; --bit) {
        const unsigned int T = Ks | (1u << bit);
        int c = 0;
        #pragma unroll
        for (int j = 0; j < 64; ++j)
            c += __popcll(__ballot(ku[j] < T));
        if (c < NTOPK) Ks = T;
    }
    int below = 0;
    #pragma unroll
    for (int j = 0; j < 64; ++j)
        below += __popcll(__ballot(ku[j] < Ks));
    const int tk = NTOPK - below;

    const float dpos = 1.0f - cpp[w];
    const int pg = p0 + w;
    const float2 gp = *(const float2*)&G[((size_t)b * NHW + pg) * 2];
    const float px = gp.x * 4096.f, py = gp.y * 4096.f;
    const float base_add = dpos + (FMARGIN - 1.0f);

    float sumv = 0.f; int cnt = 0;
    unsigned long long tmask = 0ull; int ltc = 0;
    #pragma unroll
    for (int j = 0; j < 64; ++j) {
        const unsigned int k = ku[j];
        if (k < Ks) {
            const int q = (lane << 6) + 8 * (j >> 2) + 2 * (j & 3) + half;
            bool keep = (q != pg);
            if (keep) {
                float2 g2 = *(const float2*)&G[((size_t)b * NHW + q) * 2];
                float dx = fabsf(g2.x * 4096.f - px), dy = fabsf(g2.y * 4096.f - py);
                keep = !((dx < 1.2f) && (dy < 1.2f));
            }
            if (keep) { sumv += k16tof(k); cnt++; }
        } else if (k == Ks) {
            tmask |= (1ull << j);
            ltc++;
        }
    }
    int pfx = ltc;
    #pragma unroll
    for (int d = 1; d < 64; d <<= 1) {
        int t2 = __shfl_up(pfx, d, 64);
        if (lane >= d) pfx += t2;
    }
    pfx -= ltc;
    int ek = 0;
    if (ltc > 0 && pfx < tk) {
        unsigned long long mm = tmask;
        int m = 0;
        while (mm) {
            const int j = __ffsll((unsigned long long)mm) - 1;
            mm &= mm - 1;
            if (pfx + m < tk) {
                const int q = (lane << 6) + 8 * (j >> 2) + 2 * (j & 3) + half;
                bool keep = (q != pg);
                if (keep) {
                    float2 g2 = *(const float2*)&G[((size_t)b * NHW + q) * 2];
                    float dx = fabsf(g2.x * 4096.f - px), dy = fabsf(g2.y * 4096.f - py);
                    keep = !((dx < 1.2f) && (dy < 1.2f));
                }
                if (keep) ek++;
            }
            m++;
        }
    }
    const float vstar = k16tof(Ks);
    float fl = sumv + (float)cnt * base_add + (float)ek * (base_add + vstar);
    int ccnt = cnt + ek;
    #pragma unroll
    for (int d = 1; d < 64; d <<= 1) {
        fl += __shfl_xor(fl, d, 64);
        ccnt += __shfl_xor(ccnt, d, 64);
    }
    if (lane == 0) {
        const int pv = (pvalid[b * NHW + pg] != 0) && (ccnt > 0);
        row_val[b * NHW + pg] = pv ? (fl / (float)ccnt) : 0.f;
        row_valid[b * NHW + pg] = pv;
    }
}

// ---- final deterministic reduction (1024 threads) ----
__global__ void k_reduce(const float* __restrict__ row_val, const int* __restrict__ row_valid,
                         float* __restrict__ out) {
    __shared__ float ss[1024];
    __shared__ int sc[1024];
    float s = 0.f; int n = 0;
    for (int i = threadIdx.x; i < NB * NHW; i += 1024) { s += row_val[i]; n += row_valid[i]; }
    ss[threadIdx.x] = s; sc[threadIdx.x] = n;
    __syncthreads();
    for (int d = 512; d > 0; d >>= 1) {
        if (threadIdx.x < d) { ss[threadIdx.x] += ss[threadIdx.x + d]; sc[threadIdx.x] += sc[threadIdx.x + d]; }
        __syncthreads();
    }
    if (threadIdx.x == 0) out[0] = ss[0] / (1e-6f + (float)sc[0]);
}

extern "C" void kernel_launch(void* const* d_in, const int* in_sizes, int n_in,
                              void* d_out, int out_size, void* d_ws, size_t ws_size,
                              hipStream_t stream) {
    const float* sk = (const float*)d_in[0];
    const float* rf = (const float*)d_in[1];
    const float* G  = (const float*)d_in[2];
    char* ws = (char*)d_ws;
    const size_t SMALL5 = 5ull * 65536ull;
    const size_t PANEL8 = (size_t)NB * NC * NHW;              // 4 MB
    const size_t CANDSZ = (size_t)NB * NHW * 256 * 4;         // 16.8 MB
    const size_t QNEED = SMALL5 + 2 * PANEL8 + CANDSZ;        // ~25.5 MB
    int*   ac   = (int*)  (ws + 0 * 65536);
    int*   pv   = (int*)  (ws + 1 * 65536);
    float* rv_  = (float*)(ws + 2 * 65536);
    int*   rvd  = (int*)  (ws + 3 * 65536);
    float* cppg = (float*)(ws + 4 * 65536);
    unsigned char* rf8 = (unsigned char*)(ws + SMALL5);
    unsigned char* sk8 = (unsigned char*)(ws + SMALL5 + PANEL8);
    unsigned int* cand = (unsigned int*)(ws + SMALL5 + 2 * PANEL8);

    hipLaunchKernelGGL(k_pre, dim3(576), dim3(256), 0, stream,
                       sk, rf, G, ac, pv, rf8, sk8);
    if (ws_size >= QNEED) {
        hipLaunchKernelGGL(k_part, dim3(8192), dim3(512), 0, stream,
                           rf8, sk8, ac, cppg, cand);
        hipLaunchKernelGGL(k_merge, dim3(2048), dim3(512), 0, stream,
                           cand, cppg, G, pv, rv_, rvd);
    } else {
        hipLaunchKernelGGL(k_main_r12, dim3(1024), dim3(1024), 0, stream,
                           rf8, sk8, G, ac, pv, rv_, rvd);
    }
    hipLaunchKernelGGL(k_reduce, dim3(1), dim3(1024), 0, stream, rv_, rvd, (float*)d_out);
}